// Round 3
// baseline (1471.807 us; speedup 1.0000x reference)
//
#include <hip/hip_runtime.h>
#include <hip/hip_bf16.h>
#include <stdint.h>

typedef unsigned short u16;
typedef unsigned int u32;

#define F1 274625   // 65^3
#define IJ1 4225    // 65^2

typedef float v4f __attribute__((ext_vector_type(4)));
typedef __bf16 v8bf __attribute__((ext_vector_type(8)));

static __device__ __forceinline__ float lof(u32 u) { union { u32 u; float f; } c; c.u = u << 16; return c.f; }
static __device__ __forceinline__ float hif(u32 u) { union { u32 u; float f; } c; c.u = u & 0xffff0000u; return c.f; }
static __device__ __forceinline__ u16 f2bf(float f) {
  union { float f; u32 u; } c; c.f = f;
  u32 r = (c.u >> 16) & 1u;
  return (u16)((c.u + 0x7fffu + r) >> 16);
}
static __device__ __forceinline__ u32 pkbf(float a, float b) {
  __hip_bfloat162 h = __float22bfloat162_rn(make_float2(a, b));
  union { __hip_bfloat162 h; u32 u; } c; c.h = h; return c.u;
}
static __device__ __forceinline__ u32 pkbfu(u32 a, u32 b) {
  union { u32 u; float f; } ca, cb; ca.u = a; cb.u = b; return pkbf(ca.f, cb.f);
}
static __device__ __forceinline__ v8bf mkbf(u32 a, u32 b, u32 c, u32 d) {
  union { u32 u[4]; v8bf v; } x; x.u[0] = a; x.u[1] = b; x.u[2] = c; x.u[3] = d; return x.v;
}

// ---------------- K0: transpose vec1/2/3 [512][64] f32 -> xT [3][64][512] f32
__global__ void __launch_bounds__(256) k0_transpose(const float* __restrict__ v1,
    const float* __restrict__ v2, const float* __restrict__ v3, float* __restrict__ xT) {
  int g = blockIdx.x * 256 + threadIdx.x;
  if (g >= 3 * 64 * 512) return;
  int t = g >> 15, r = g & 32767;
  int d = r >> 9, b = r & 511;
  const float* v = (t == 0) ? v1 : ((t == 1) ? v2 : v3);
  xT[g] = v[b * 64 + d];
}

// ---------------- K1: bilinear partial sums -> zsum [3][64][512] f32 (atomic)
__global__ void __launch_bounds__(256) k1_bilinear(
    const float* __restrict__ zw1, const float* __restrict__ zw2, const float* __restrict__ zw3,
    const float* __restrict__ xT, float* __restrict__ zsum) {
  int bid = blockIdx.x;                 // 768 = t*256 + o*4 + bh*2 + ih
  int ih = bid & 1, bh = (bid >> 1) & 1;
  int o = (bid >> 2) & 63, t = bid >> 8;
  int b = bh * 256 + threadIdx.x;
  const float* zw = (t == 0) ? zw1 : ((t == 1) ? zw2 : zw3);
  const float* xiT = xT + ((t == 1) ? 32768 : 0);
  const float* x3T = xT + 65536;
  float x3r[64];
#pragma unroll
  for (int j = 0; j < 64; ++j) x3r[j] = x3T[j * 512 + b];
  const float4* w4 = (const float4*)(zw + o * 4096);
  float acc = 0.f;
  int i0 = ih * 32;
#pragma unroll 2
  for (int i = i0; i < i0 + 32; ++i) {
    float xi = xiT[i * 512 + b];
    float s = 0.f;
#pragma unroll
    for (int q = 0; q < 16; ++q) {
      float4 w = w4[i * 16 + q];
      s += w.x * x3r[q*4+0] + w.y * x3r[q*4+1] + w.z * x3r[q*4+2] + w.w * x3r[q*4+3];
    }
    acc += xi * s;
  }
  atomicAdd(&zsum[t * 32768 + o * 512 + b], acc);
}

// ---------------- K2: per-branch h/o layers -> oT f32 [3][65][512], o3row bf16 [512][72]
__global__ void __launch_bounds__(256) k2_branch(
    const float* __restrict__ hw1, const float* __restrict__ hb1,
    const float* __restrict__ ow1, const float* __restrict__ ob1,
    const float* __restrict__ hw2, const float* __restrict__ hb2,
    const float* __restrict__ ow2, const float* __restrict__ ob2,
    const float* __restrict__ hw3, const float* __restrict__ hb3,
    const float* __restrict__ ow3, const float* __restrict__ ob3,
    const float* __restrict__ zb1, const float* __restrict__ zb2, const float* __restrict__ zb3,
    const float* __restrict__ xT, const float* __restrict__ zsum,
    float* __restrict__ oT, u16* __restrict__ o3row) {
  int t = blockIdx.x >> 3, bc = blockIdx.x & 7;   // 24 blocks
  int lane = threadIdx.x & 63;
  int w = __builtin_amdgcn_readfirstlane((int)(threadIdx.x >> 6));
  int b = bc * 64 + lane;
  const float* hw = (t==0)?hw1:((t==1)?hw2:hw3);
  const float* hb = (t==0)?hb1:((t==1)?hb2:hb3);
  const float* ow = (t==0)?ow1:((t==1)?ow2:ow3);
  const float* ob = (t==0)?ob1:((t==1)?ob2:ob3);
  const float* zb = (t==0)?zb1:((t==1)?zb2:zb3);
  const float* xtT = xT + t * 32768;
  const float4* hw4 = (const float4*)hw;
  const float4* ow4 = (const float4*)ow;
  __shared__ float gT[64][68];
  float xr[64];
#pragma unroll
  for (int k = 0; k < 64; ++k) xr[k] = xtT[k * 512 + b];
#pragma unroll
  for (int ii = 0; ii < 16; ii += 4) {
    float gv[4];
#pragma unroll
    for (int q = 0; q < 4; ++q) {
      int i = w * 16 + ii + q;
      float a = hb[i];
#pragma unroll
      for (int kq = 0; kq < 16; ++kq) {
        float4 h4 = hw4[i * 16 + kq];
        a += h4.x * xr[kq*4+0] + h4.y * xr[kq*4+1] + h4.z * xr[kq*4+2] + h4.w * xr[kq*4+3];
      }
      float hv = fmaxf(a, 0.f);
      float z = zsum[t * 32768 + i * 512 + b] + zb[i];
      float sg = 1.f / (1.f + __expf(-z));
      gv[q] = sg * hv;
    }
    *(float4*)&gT[lane][w * 16 + ii] = make_float4(gv[0], gv[1], gv[2], gv[3]);
  }
  __syncthreads();
  float gr[64];
#pragma unroll
  for (int k = 0; k < 64; k += 4) {
    float4 g4 = *(const float4*)&gT[lane][k];
    gr[k] = g4.x; gr[k+1] = g4.y; gr[k+2] = g4.z; gr[k+3] = g4.w;
  }
#pragma unroll
  for (int ii = 0; ii < 16; ++ii) {
    int oo = w * 16 + ii;
    float a = ob[oo];
#pragma unroll
    for (int kq = 0; kq < 16; ++kq) {
      float4 o4 = ow4[oo * 16 + kq];
      a += o4.x * gr[kq*4+0] + o4.y * gr[kq*4+1] + o4.z * gr[kq*4+2] + o4.w * gr[kq*4+3];
    }
    float ov = fmaxf(a, 0.f);
    oT[(t * 65 + oo) * 512 + b] = ov;
    if (t == 2) o3row[b * 72 + oo] = f2bf(ov);
  }
  if (w == 0) oT[(t * 65 + 64) * 512 + b] = 1.f;
  if (t == 2 && w == 1) {
    uint4 ones = make_uint4(0x3F80u, 0u, 0u, 0u);   // bf16 1.0 then zeros (cols 64..71)
    *(uint4*)&o3row[b * 72 + 64] = ones;
  }
}

// ---------------- K3: o12b bf16 [4225][512] = o1[b,i]*o2[b,j]
__global__ void __launch_bounds__(256) k3_o12(const float* __restrict__ oT, u16* __restrict__ o12b) {
  int total = IJ1 * 512;
  for (int g = blockIdx.x * 256 + threadIdx.x; g < total; g += gridDim.x * 256) {
    int ij = g >> 9, b = g & 511;
    int i = ij / 65, j = ij - i * 65;
    o12b[g] = f2bf(oT[i * 512 + b] * oT[(65 + j) * 512 + b]);
  }
}

// ---------------- K4: main GEMM. grid 512 = m*128 + (sK*2+n); block 512 thr (8 waves).
// Wave w owns m-rows [w*16,w*16+16) x all 128 n-cols. Scale o12 folded into A;
// ones-column folded via 3rd K-step. Output -> partial[sK][b][o] (or atomic fallback).
__global__ void __launch_bounds__(512, 4) k4_gemm(
    const float* __restrict__ W, const u16* __restrict__ o3row,
    const u16* __restrict__ o12b, float* __restrict__ accum,
    float* __restrict__ partial) {
  __shared__ u16 Bs[2][9216];     // [128 rows][72] bf16, cols 65..71 zero
  __shared__ u16 o12s[2][128];
  __shared__ u16 ldspad[16];      // OOB-read slack for kstep2 lkg>0 reads
  int bid = blockIdx.x;
  int m = bid >> 7, r = bid & 127;
  int sK = r >> 1, n = r & 1;
  int mbase = m << 7, nbase = n << 7;
  int ij0 = (sK * IJ1) >> 6, ij1 = ((sK + 1) * IJ1) >> 6;
  int tid = threadIdx.x;
  int lane = tid & 63;
  int w = __builtin_amdgcn_readfirstlane(tid >> 6);
  int lrow = lane & 15, lkg = lane >> 4;
  // persistent A-side o3 data: row mbase+w*16+lrow, k = lkg*8..(+7) and 32+lkg*8..
  u32 o3u8[8];
  {
    const uint4* p0 = (const uint4*)(o3row + (mbase + w * 16 + lrow) * 72 + lkg * 8);
    uint4 a = p0[0], b = p0[4];   // +4 uint4 = +32 bf16 elements
    o3u8[0]=a.x; o3u8[1]=a.y; o3u8[2]=a.z; o3u8[3]=a.w;
    o3u8[4]=b.x; o3u8[5]=b.y; o3u8[6]=b.z; o3u8[7]=b.w;
  }
  // staging mapping: 4 threads per row
  int rr = tid >> 2, c = tid & 3;
  long growBase = (long)(nbase + rr) * F1;
  const uint4* Wq = (const uint4*)W;
  const long u4cap = (256L * F1) / 4 - 1;
  // zero cols 64..71 of both buffers (col64 rewritten per ij; 65..71 stay 0)
  if (tid < 128) {
    uint4 z = make_uint4(0,0,0,0);
    *(uint4*)&Bs[0][tid * 72 + 64] = z;
    *(uint4*)&Bs[1][tid * 72 + 64] = z;
  }
  v4f acc[8] = {};
  (void)ldspad;

  // ---- stage ij0 into buf 0
  {
    long g0 = growBase + (long)ij0 * 65;
    int s4 = (int)(g0 & 3);
    long ub = (g0 >> 2) + (long)(c << 2);
    long i0 = ub+0 > u4cap ? u4cap : ub+0;
    long i1 = ub+1 > u4cap ? u4cap : ub+1;
    long i2 = ub+2 > u4cap ? u4cap : ub+2;
    long i3 = ub+3 > u4cap ? u4cap : ub+3;
    long i4 = ub+4 > u4cap ? u4cap : ub+4;
    uint4 q0 = Wq[i0], q1 = Wq[i1], q2 = Wq[i2], q3 = Wq[i3], q4 = Wq[i4];
    u32 L[20] = {q0.x,q0.y,q0.z,q0.w, q1.x,q1.y,q1.z,q1.w, q2.x,q2.y,q2.z,q2.w,
                 q3.x,q3.y,q3.z,q3.w, q4.x,q4.y,q4.z,q4.w};
    u32 A_[18], Bv[17];
#pragma unroll
    for (int j = 0; j < 18; ++j) A_[j] = (s4 & 2) ? L[j + 2] : L[j];
#pragma unroll
    for (int j = 0; j < 17; ++j) Bv[j] = (s4 & 1) ? A_[j + 1] : A_[j];
    u32 Pk[8];
#pragma unroll
    for (int t = 0; t < 8; ++t) Pk[t] = pkbfu(Bv[2*t], Bv[2*t+1]);
    u16* bp = &Bs[0][rr * 72 + (c << 4)];
    *(uint4*)(bp)     = make_uint4(Pk[0], Pk[1], Pk[2], Pk[3]);
    *(uint4*)(bp + 8) = make_uint4(Pk[4], Pk[5], Pk[6], Pk[7]);
    if (c == 3) Bs[0][rr * 72 + 64] = (u16)(pkbfu(Bv[16], Bv[16]) & 0xffffu);
    if (tid < 16)
      ((uint4*)o12s[0])[tid] = ((const uint4*)(o12b + ij0 * 512 + mbase))[tid];
  }
  __syncthreads();

  int p = 0;
  for (int ij = ij0; ij < ij1; ++ij) {
    // ---- issue prefetch loads for ij+1
    bool more = (ij + 1 < ij1);
    uint4 q0, q1, q2, q3, q4; int s4n = 0;
    if (more) {
      long g0 = growBase + (long)(ij + 1) * 65;
      s4n = (int)(g0 & 3);
      long ub = (g0 >> 2) + (long)(c << 2);
      long i0 = ub+0 > u4cap ? u4cap : ub+0;
      long i1 = ub+1 > u4cap ? u4cap : ub+1;
      long i2 = ub+2 > u4cap ? u4cap : ub+2;
      long i3 = ub+3 > u4cap ? u4cap : ub+3;
      long i4 = ub+4 > u4cap ? u4cap : ub+4;
      q0 = Wq[i0]; q1 = Wq[i1]; q2 = Wq[i2]; q3 = Wq[i3]; q4 = Wq[i4];
    }
    // ---- MFMA on buffer p
    {
      float s = lof((u32)o12s[p][w * 16 + lrow]);
      u32 Au[12];
#pragma unroll
      for (int t = 0; t < 8; ++t) Au[t] = pkbf(s * lof(o3u8[t]), s * hif(o3u8[t]));
      Au[8] = (lkg == 0) ? pkbf(s, 0.f) : 0u;
      Au[9] = Au[10] = Au[11] = 0u;
      v8bf af0 = mkbf(Au[0], Au[1], Au[2], Au[3]);
      v8bf af1 = mkbf(Au[4], Au[5], Au[6], Au[7]);
      v8bf af2 = mkbf(Au[8], Au[9], Au[10], Au[11]);
#pragma unroll
      for (int u = 0; u < 8; ++u) {
        const u16* bb = &Bs[p][(u * 16 + lrow) * 72 + lkg * 8];
        v8bf b0 = *(const v8bf*)bb;
        v8bf b1 = *(const v8bf*)(bb + 32);
        v8bf b2 = *(const v8bf*)(&Bs[p][(u * 16 + lrow) * 72 + 64 + lkg * 8]);
        acc[u] = __builtin_amdgcn_mfma_f32_16x16x32_bf16(af0, b0, acc[u], 0, 0, 0);
        acc[u] = __builtin_amdgcn_mfma_f32_16x16x32_bf16(af1, b1, acc[u], 0, 0, 0);
        acc[u] = __builtin_amdgcn_mfma_f32_16x16x32_bf16(af2, b2, acc[u], 0, 0, 0);
      }
    }
    // ---- realign + convert + write buffer p^1
    if (more) {
      u32 L[20] = {q0.x,q0.y,q0.z,q0.w, q1.x,q1.y,q1.z,q1.w, q2.x,q2.y,q2.z,q2.w,
                   q3.x,q3.y,q3.z,q3.w, q4.x,q4.y,q4.z,q4.w};
      u32 A_[18], Bv[17];
#pragma unroll
      for (int j = 0; j < 18; ++j) A_[j] = (s4n & 2) ? L[j + 2] : L[j];
#pragma unroll
      for (int j = 0; j < 17; ++j) Bv[j] = (s4n & 1) ? A_[j + 1] : A_[j];
      u32 Pk[8];
#pragma unroll
      for (int t = 0; t < 8; ++t) Pk[t] = pkbfu(Bv[2*t], Bv[2*t+1]);
      u16* bp = &Bs[p ^ 1][rr * 72 + (c << 4)];
      *(uint4*)(bp)     = make_uint4(Pk[0], Pk[1], Pk[2], Pk[3]);
      *(uint4*)(bp + 8) = make_uint4(Pk[4], Pk[5], Pk[6], Pk[7]);
      if (c == 3) Bs[p ^ 1][rr * 72 + 64] = (u16)(pkbfu(Bv[16], Bv[16]) & 0xffffu);
      if (tid < 16)
        ((uint4*)o12s[p ^ 1])[tid] = ((const uint4*)(o12b + (ij + 1) * 512 + mbase))[tid];
    }
    __syncthreads();
    p ^= 1;
  }

  // ---- epilogue: C/D layout col=lane&15, row=(lane>>4)*4+e
  int gb0 = mbase + w * 16 + lkg * 4;
  if (partial) {
    float* pb = partial + ((long)sK << 17);
#pragma unroll
    for (int u = 0; u < 8; ++u) {
      int go = nbase + u * 16 + lrow;
#pragma unroll
      for (int e = 0; e < 4; ++e) pb[(gb0 + e) * 256 + go] = acc[u][e];
    }
  } else {
#pragma unroll
    for (int u = 0; u < 8; ++u) {
      int go = nbase + u * 16 + lrow;
#pragma unroll
      for (int e = 0; e < 4; ++e) atomicAdd(&accum[(gb0 + e) * 256 + go], acc[u][e]);
    }
  }
}

// ---------------- K6: reduce 64 partial copies -> accum
__global__ void __launch_bounds__(256) k6_reduce(const float* __restrict__ partial,
                                                 float* __restrict__ accum) {
  int idx = blockIdx.x * 256 + threadIdx.x;   // grid 512 -> 131072
  float s = 0.f;
#pragma unroll 16
  for (int k = 0; k < 64; ++k) s += partial[((long)k << 17) + idx];
  accum[idx] = s;
}

// ---------------- K5: enc2 with relu(enc1)+skip concat -> out f32 [512][256]
__global__ void __launch_bounds__(256) k5_enc2(
    const float* __restrict__ accum, const float* __restrict__ oT,
    const float* __restrict__ enc1b, const float* __restrict__ w2,
    const float* __restrict__ enc2b, float* __restrict__ outp) {
  int bg = blockIdx.x >> 3, og = blockIdx.x & 7;   // 64 blocks
  int lane = threadIdx.x & 63;
  int w = __builtin_amdgcn_readfirstlane((int)(threadIdx.x >> 6));
  int b = bg * 64 + lane;
  int obase = og * 32 + w * 8;
  float a8[8];
#pragma unroll
  for (int q = 0; q < 8; ++q) a8[q] = enc2b[obase + q];
  for (int c = 0; c < 256; ++c) {
    float x = fmaxf(accum[b * 256 + c] + enc1b[c], 0.f);
#pragma unroll
    for (int q = 0; q < 8; ++q) a8[q] += w2[(obase + q) * 451 + c] * x;
  }
  for (int e = 0; e < 195; ++e) {
    float x = oT[e * 512 + b];
#pragma unroll
    for (int q = 0; q < 8; ++q) a8[q] += w2[(obase + q) * 451 + 256 + e] * x;
  }
#pragma unroll
  for (int q = 0; q < 8; ++q) outp[b * 256 + obase + q] = fmaxf(a8[q], 0.f);
}

extern "C" void kernel_launch(void* const* d_in, const int* in_sizes, int n_in,
                              void* d_out, int out_size, void* d_ws, size_t ws_size,
                              hipStream_t stream) {
  const float* vec1 = (const float*)d_in[0];
  const float* vec2 = (const float*)d_in[1];
  const float* vec3 = (const float*)d_in[2];
  const float* h1w = (const float*)d_in[3];  const float* h1b = (const float*)d_in[4];
  const float* z1w = (const float*)d_in[5];  const float* z1b = (const float*)d_in[6];
  const float* o1w = (const float*)d_in[7];  const float* o1b = (const float*)d_in[8];
  const float* h2w = (const float*)d_in[9];  const float* h2b = (const float*)d_in[10];
  const float* z2w = (const float*)d_in[11]; const float* z2b = (const float*)d_in[12];
  const float* o2w = (const float*)d_in[13]; const float* o2b = (const float*)d_in[14];
  const float* h3w = (const float*)d_in[15]; const float* h3b = (const float*)d_in[16];
  const float* z3w = (const float*)d_in[17]; const float* z3b = (const float*)d_in[18];
  const float* o3w = (const float*)d_in[19]; const float* o3b = (const float*)d_in[20];
  const float* e1w = (const float*)d_in[21]; const float* e1b = (const float*)d_in[22];
  const float* e2w = (const float*)d_in[23]; const float* e2b = (const float*)d_in[24];

  char* ws = (char*)d_ws;
  float* accum = (float*)(ws + 0);              // 524288
  float* oT    = (float*)(ws + 524288);         // 399360
  u16* o3row   = (u16*)  (ws + 923648);         // 73728
  u16* o12b    = (u16*)  (ws + 997376);         // 4326400
  float* xT    = (float*)(ws + 5323776);        // 393216
  float* zsum  = (float*)(ws + 5716992);        // 393216
  size_t partial_off = 6110208;
  size_t partial_bytes = (size_t)64 * 131072 * 4;   // 33.5 MB
  float* partial = (ws_size >= partial_off + partial_bytes) ? (float*)(ws + partial_off)
                                                            : (float*)nullptr;

  hipMemsetAsync(accum, 0, 524288, stream);
  hipMemsetAsync(zsum, 0, 393216, stream);

  hipLaunchKernelGGL(k0_transpose, dim3(384), dim3(256), 0, stream, vec1, vec2, vec3, xT);
  hipLaunchKernelGGL(k1_bilinear, dim3(768), dim3(256), 0, stream, z1w, z2w, z3w, xT, zsum);
  hipLaunchKernelGGL(k2_branch, dim3(24), dim3(256), 0, stream,
                     h1w, h1b, o1w, o1b, h2w, h2b, o2w, o2b, h3w, h3b, o3w, o3b,
                     z1b, z2b, z3b, xT, zsum, oT, o3row);
  hipLaunchKernelGGL(k3_o12, dim3(2048), dim3(256), 0, stream, oT, o12b);
  hipLaunchKernelGGL(k4_gemm, dim3(512), dim3(512), 0, stream, e1w, o3row, o12b, accum, partial);
  if (partial)
    hipLaunchKernelGGL(k6_reduce, dim3(512), dim3(256), 0, stream, partial, accum);
  hipLaunchKernelGGL(k5_enc2, dim3(64), dim3(256), 0, stream, accum, oT, e1b, e2w, e2b,
                     (float*)d_out);
}